// Round 4
// baseline (294.603 us; speedup 1.0000x reference)
//
#include <hip/hip_runtime.h>

// x [16,64,224,224] fp32 -> 2x2 patches -> MLP 4->16(relu)->1 -> out [16,64,112,112] fp32.
// Memory-bound floor: 205 MB read + 51 MB write => ~41 us at 6.3 TB/s.
//
// r = img*112 + i (fused row index):
//   input  = x   + r*448 + 8*j   (row 2i; +224 floats for row 2i+1), j in [0,28)
//   output = out + r*112 + 4*j
// One thread = 4 adjacent patches (8 input cols): 4x float4 loads, 1x float4 store.
// MLP computed in float2 packed form -> v_pk_fma_f32.

typedef float v2f __attribute__((ext_vector_type(2)));

#define NJ4 28  // float4-output groups per output row (112/4)

__global__ __launch_bounds__(256)
void nn_pool_kernel(const float* __restrict__ x,
                    const float* __restrict__ W1,   // [16][4]
                    const float* __restrict__ b1,   // [16]
                    const float* __restrict__ W2,   // [16]
                    const float* __restrict__ b2,   // [1]
                    float* __restrict__ out)
{
    const int tid = blockIdx.x * 256 + threadIdx.x;
    const int j = tid % NJ4;
    const int r = tid / NJ4;   // r = img*112 + i

    // Issue all 4 HBM loads up front; uniform weight s_loads hide under them.
    const float* p0 = x + r * 448 + j * 8;                          // cols 8j..8j+7, row 2i
    const float4 r0a = *reinterpret_cast<const float4*>(p0);        // row 2i,   cols 8j..8j+3
    const float4 r0b = *reinterpret_cast<const float4*>(p0 + 4);    // row 2i,   cols 8j+4..8j+7
    const float4 r1a = *reinterpret_cast<const float4*>(p0 + 224);  // row 2i+1, cols 8j..8j+3
    const float4 r1b = *reinterpret_cast<const float4*>(p0 + 228);  // row 2i+1, cols 8j+4..8j+7

    const float c2 = b2[0];

    // Pair A = patches (0,1), pair B = patches (2,3); component k of each patch.
    const v2f a0 = {r0a.x, r0a.z}, a1 = {r0a.y, r0a.w};
    const v2f a2 = {r1a.x, r1a.z}, a3 = {r1a.y, r1a.w};
    const v2f c0 = {r0b.x, r0b.z}, c1 = {r0b.y, r0b.w};
    const v2f c2v = {r1b.x, r1b.z}, c3 = {r1b.y, r1b.w};

    v2f accA = {c2, c2}, accB = {c2, c2};
#pragma unroll
    for (int h = 0; h < 16; ++h) {
        const float w0 = W1[4 * h + 0];
        const float w1 = W1[4 * h + 1];
        const float w2 = W1[4 * h + 2];
        const float w3 = W1[4 * h + 3];
        const float bb = b1[h];
        const float vv = W2[h];

        v2f sA = {bb, bb}, sB = {bb, bb};
        sA = __builtin_elementwise_fma(a0, (v2f){w0, w0}, sA);
        sB = __builtin_elementwise_fma(c0, (v2f){w0, w0}, sB);
        sA = __builtin_elementwise_fma(a1, (v2f){w1, w1}, sA);
        sB = __builtin_elementwise_fma(c1, (v2f){w1, w1}, sB);
        sA = __builtin_elementwise_fma(a2, (v2f){w2, w2}, sA);
        sB = __builtin_elementwise_fma(c2v, (v2f){w2, w2}, sB);
        sA = __builtin_elementwise_fma(a3, (v2f){w3, w3}, sA);
        sB = __builtin_elementwise_fma(c3, (v2f){w3, w3}, sB);
        sA = __builtin_elementwise_max(sA, (v2f){0.f, 0.f});
        sB = __builtin_elementwise_max(sB, (v2f){0.f, 0.f});
        accA = __builtin_elementwise_fma(sA, (v2f){vv, vv}, accA);
        accB = __builtin_elementwise_fma(sB, (v2f){vv, vv}, accB);
    }

    float4 res;
    res.x = accA.x; res.y = accA.y; res.z = accB.x; res.w = accB.y;
    *reinterpret_cast<float4*>(out + r * 112 + j * 4) = res;
}

extern "C" void kernel_launch(void* const* d_in, const int* in_sizes, int n_in,
                              void* d_out, int out_size, void* d_ws, size_t ws_size,
                              hipStream_t stream) {
    const float* x  = (const float*)d_in[0];
    const float* W1 = (const float*)d_in[1];
    const float* b1 = (const float*)d_in[2];
    const float* W2 = (const float*)d_in[3];
    const float* b2 = (const float*)d_in[4];
    float* out = (float*)d_out;

    // out_size/4 = 3,211,264 quads; 3,211,264 / 256 = 12544 blocks exactly (no tail).
    const int n_quads = out_size / 4;
    const int block = 256;
    const int grid = n_quads / block;
    nn_pool_kernel<<<grid, block, 0, stream>>>(x, W1, b1, W2, b2, out);
}